// Round 1
// baseline (708.989 us; speedup 1.0000x reference)
//
#include <hip/hip_runtime.h>
#include <stdint.h>

#define N_TOKENS 32768
#define N_CODES  8192
#define DIM      256
#define EPSF     1e-8f

typedef __bf16 bf16x8 __attribute__((ext_vector_type(8)));
typedef float  f32x4  __attribute__((ext_vector_type(4)));

// ---------------------------------------------------------------------------
// ws layout: [bf16 codebooks 4MiB][cnorm f32 32KiB][idx i32 128KiB][hist i32 32KiB]
// ---------------------------------------------------------------------------
#define WS_CNORM_OFF  (4u*1024u*1024u)
#define WS_IDX_OFF    (WS_CNORM_OFF + N_CODES*4u)
#define WS_HIST_OFF   (WS_IDX_OFF + N_TOKENS*4u)

// ---------------------------------------------------------------------------
// K1: convert codebooks fp32 -> bf16, compute ||c||^2, zero histogram.
// grid: N_CODES/4 blocks x 256 thr (one wave per codebook row)
// ---------------------------------------------------------------------------
__global__ __launch_bounds__(256) void k_prep(const float* __restrict__ cbf,
                                              unsigned short* __restrict__ cbh,
                                              float* __restrict__ cnorm,
                                              int* __restrict__ hist) {
    const int tid = blockIdx.x * 256 + threadIdx.x;
    if (tid < N_CODES) hist[tid] = 0;

    const int w = threadIdx.x >> 6;
    const int lane = threadIdx.x & 63;
    const int row = blockIdx.x * 4 + w;

    const float4 v = ((const float4*)(cbf + (size_t)row * DIM))[lane];
    float sq = v.x * v.x + v.y * v.y + v.z * v.z + v.w * v.w;

    ushort4 u;
    u.x = __builtin_bit_cast(unsigned short, (__bf16)v.x);
    u.y = __builtin_bit_cast(unsigned short, (__bf16)v.y);
    u.z = __builtin_bit_cast(unsigned short, (__bf16)v.z);
    u.w = __builtin_bit_cast(unsigned short, (__bf16)v.w);
    ((ushort4*)(cbh + (size_t)row * DIM))[lane] = u;

    #pragma unroll
    for (int d = 1; d < 64; d <<= 1) sq += __shfl_xor(sq, d);
    if (lane == 0) cnorm[row] = sq;
}

// ---------------------------------------------------------------------------
// K2: fused distance-matmul + argmin.
// block = 64 tokens, 256 thr (4 waves). Each wave owns a 16-code column slice
// of each 64-code chunk; all waves share the block's 64 token rows.
// A (tokens, bf16) lives entirely in registers: A[4 mfrag][8 kchunk].
// B (codebooks) staged per 64-code chunk into padded LDS.
// d2 = ||c||^2 - 2 x.c  (||x||^2 dropped: row-constant, argmin-invariant)
// ---------------------------------------------------------------------------
__global__ __launch_bounds__(256, 2) void k_argmin(const float* __restrict__ X,
                                                   const unsigned short* __restrict__ cbh,
                                                   const float* __restrict__ cnorm,
                                                   int* __restrict__ idxout) {
    // 64 codes x 264 shorts (pad 8 shorts -> row stride 528B = 132 dw = 4 mod 32 banks)
    __shared__ unsigned short Bs[64][264];
    __shared__ float redv[4][64];
    __shared__ int   redi[4][64];

    const int tid  = threadIdx.x;
    const int w    = tid >> 6;
    const int lane = tid & 63;
    const int lr   = lane & 15;   // fragment row/col-within-16
    const int lq   = lane >> 4;   // fragment quad
    const int r0   = blockIdx.x * 64;

    // ---- A fragments: 64 rows x 256 dims bf16, in registers (128 VGPR) ----
    bf16x8 A[4][8];
    #pragma unroll
    for (int mf = 0; mf < 4; ++mf) {
        const float* xr = X + (size_t)(r0 + mf * 16 + lr) * DIM;
        #pragma unroll
        for (int kc = 0; kc < 8; ++kc) {
            const float4 a0 = *(const float4*)(xr + kc * 32 + lq * 8);
            const float4 a1 = *(const float4*)(xr + kc * 32 + lq * 8 + 4);
            bf16x8 f;
            f[0] = (__bf16)a0.x; f[1] = (__bf16)a0.y; f[2] = (__bf16)a0.z; f[3] = (__bf16)a0.w;
            f[4] = (__bf16)a1.x; f[5] = (__bf16)a1.y; f[6] = (__bf16)a1.z; f[7] = (__bf16)a1.w;
            A[mf][kc] = f;
        }
    }

    float minv[4][4];
    int   mini[4][4];
    #pragma unroll
    for (int mf = 0; mf < 4; ++mf)
        #pragma unroll
        for (int r = 0; r < 4; ++r) { minv[mf][r] = 3.4e38f; mini[mf][r] = 0; }

    // ---- staging map: 256 thr x 8 uint4 = 32KB (64 codes x 512B) per chunk ----
    const int baseRow = tid >> 5;   // 0..7
    const int scol    = tid & 31;   // uint4 column within a 512B code row
    const uint4* CB4  = (const uint4*)cbh;

    uint4 g[8];
    #pragma unroll
    for (int i = 0; i < 8; ++i)
        g[i] = CB4[(size_t)(baseRow + 8 * i) * 32 + scol];

    const int mycol = w * 16 + lr;  // this lane's code column within the chunk

    for (int cc = 0; cc < 128; ++cc) {
        __syncthreads();   // previous chunk's MFMA reads done
        #pragma unroll
        for (int i = 0; i < 8; ++i)
            *(uint4*)&Bs[baseRow + 8 * i][scol * 8] = g[i];
        __syncthreads();

        // prefetch next chunk (overlaps MFMA section)
        const int nc = (cc + 1 < 128) ? cc + 1 : 127;
        #pragma unroll
        for (int i = 0; i < 8; ++i)
            g[i] = CB4[(size_t)(nc * 64 + baseRow + 8 * i) * 32 + scol];

        const float cn = cnorm[cc * 64 + mycol];

        f32x4 acc[4];
        #pragma unroll
        for (int mf = 0; mf < 4; ++mf) {
            acc[mf][0] = 0.f; acc[mf][1] = 0.f; acc[mf][2] = 0.f; acc[mf][3] = 0.f;
        }

        #pragma unroll
        for (int kc = 0; kc < 8; ++kc) {
            const bf16x8 b = *(const bf16x8*)&Bs[mycol][kc * 32 + lq * 8];
            #pragma unroll
            for (int mf = 0; mf < 4; ++mf)
                acc[mf] = __builtin_amdgcn_mfma_f32_16x16x32_bf16(A[mf][kc], b, acc[mf], 0, 0, 0);
        }

        const int col = cc * 64 + mycol;
        #pragma unroll
        for (int mf = 0; mf < 4; ++mf)
            #pragma unroll
            for (int r = 0; r < 4; ++r) {
                const float d2 = fmaf(-2.f, acc[mf][r], cn);
                if (d2 < minv[mf][r]) { minv[mf][r] = d2; mini[mf][r] = col; }
            }
    }

    // ---- reduce across the 16 lanes sharing each row (lr dimension) ----
    #pragma unroll
    for (int mf = 0; mf < 4; ++mf)
        #pragma unroll
        for (int r = 0; r < 4; ++r) {
            float v = minv[mf][r]; int ix = mini[mf][r];
            #pragma unroll
            for (int d = 1; d <= 8; d <<= 1) {
                const float ov = __shfl_xor(v, d);
                const int   oi = __shfl_xor(ix, d);
                if (ov < v || (ov == v && oi < ix)) { v = ov; ix = oi; }
            }
            if (lr == 0) {
                const int row = mf * 16 + lq * 4 + r;
                redv[w][row] = v; redi[w][row] = ix;
            }
        }
    __syncthreads();

    // ---- reduce across the 4 waves (different column windows, same rows) ----
    if (tid < 64) {
        float v = redv[0][tid]; int ix = redi[0][tid];
        #pragma unroll
        for (int ww = 1; ww < 4; ++ww) {
            const float ov = redv[ww][tid]; const int oi = redi[ww][tid];
            if (ov < v || (ov == v && oi < ix)) { v = ov; ix = oi; }
        }
        idxout[r0 + tid] = ix;
    }
}

// ---------------------------------------------------------------------------
// K3: exact fp32 epilogue: r_norm, n_norm, output write, histogram.
// one wave per token; grid N_TOKENS/4 x 256 thr
// ---------------------------------------------------------------------------
__global__ __launch_bounds__(256) void k_quant(const float* __restrict__ X,
                                               const float* __restrict__ R,
                                               const float* __restrict__ C,
                                               const int* __restrict__ idx,
                                               float* __restrict__ out,
                                               int* __restrict__ hist) {
    const int w = threadIdx.x >> 6;
    const int lane = threadIdx.x & 63;
    const int tok = blockIdx.x * 4 + w;
    const int k = idx[tok];

    const float4 x = ((const float4*)(X + (size_t)tok * DIM))[lane];
    const float4 r = ((const float4*)(R + (size_t)tok * DIM))[lane];
    const float4 c = ((const float4*)(C + (size_t)k * DIM))[lane];

    const float d0 = x.x - c.x, d1 = x.y - c.y, d2 = x.z - c.z, d3 = x.w - c.w;
    float r2 = d0 * d0 + d1 * d1 + d2 * d2 + d3 * d3;
    float n2 = r.x * r.x + r.y * r.y + r.z * r.z + r.w * r.w;
    #pragma unroll
    for (int d = 1; d < 64; d <<= 1) {
        r2 += __shfl_xor(r2, d);
        n2 += __shfl_xor(n2, d);
    }
    const float s = sqrtf(r2) / (sqrtf(n2) + EPSF);

    float4 o;
    o.x = fmaf(s, r.x, x.x);
    o.y = fmaf(s, r.y, x.y);
    o.z = fmaf(s, r.z, x.z);
    o.w = fmaf(s, r.w, x.w);
    ((float4*)(out + (size_t)tok * DIM))[lane] = o;

    if (lane == 0) atomicAdd(&hist[k], 1);
}

// ---------------------------------------------------------------------------
// K4: perplexity + num_unique from histogram. single block.
// ---------------------------------------------------------------------------
__global__ __launch_bounds__(256) void k_stats(const int* __restrict__ hist,
                                               float* __restrict__ outs) {
    float s = 0.f; int u = 0;
    for (int b = threadIdx.x; b < N_CODES; b += 256) {
        const float c = (float)hist[b];
        if (c > 0.f) ++u;
        const float p = c * (1.f / (float)N_TOKENS);
        s += p * logf(p + EPSF);
    }
    #pragma unroll
    for (int d = 1; d < 64; d <<= 1) {
        s += __shfl_xor(s, d);
        u += __shfl_xor(u, d);
    }
    __shared__ float ss[4];
    __shared__ int   su[4];
    const int w = threadIdx.x >> 6, lane = threadIdx.x & 63;
    if (lane == 0) { ss[w] = s; su[w] = u; }
    __syncthreads();
    if (threadIdx.x == 0) {
        const float st = ss[0] + ss[1] + ss[2] + ss[3];
        const int ut = su[0] + su[1] + su[2] + su[3];
        outs[0] = expf(-st);       // perplexity
        outs[1] = (float)ut;       // num_unique_indices
    }
}

// ---------------------------------------------------------------------------
extern "C" void kernel_launch(void* const* d_in, const int* in_sizes, int n_in,
                              void* d_out, int out_size, void* d_ws, size_t ws_size,
                              hipStream_t stream) {
    const float* X = (const float*)d_in[0];  // input_data (32768,256)
    const float* R = (const float*)d_in[1];  // rand       (32768,256)
    const float* C = (const float*)d_in[2];  // codebooks  (8192,256)
    float* out = (float*)d_out;

    char* ws = (char*)d_ws;
    unsigned short* cbh = (unsigned short*)ws;             // bf16 codebooks
    float* cnorm = (float*)(ws + WS_CNORM_OFF);
    int*   idx   = (int*)(ws + WS_IDX_OFF);
    int*   hist  = (int*)(ws + WS_HIST_OFF);

    k_prep  <<<N_CODES / 4,  256, 0, stream>>>(C, cbh, cnorm, hist);
    k_argmin<<<N_TOKENS / 64, 256, 0, stream>>>(X, cbh, cnorm, idx);
    k_quant <<<N_TOKENS / 4, 256, 0, stream>>>(X, R, C, idx, out, hist);
    k_stats <<<1, 256, 0, stream>>>(hist, out + (size_t)N_TOKENS * DIM);
}

// Round 2
// 282.748 us; speedup vs baseline: 2.5075x; 2.5075x over previous
//
#include <hip/hip_runtime.h>
#include <stdint.h>

#define N_TOKENS 32768
#define N_CODES  8192
#define DIM      256
#define EPSF     1e-8f

typedef __bf16 bf16x8 __attribute__((ext_vector_type(8)));
typedef float  f32x4  __attribute__((ext_vector_type(4)));

// ---------------------------------------------------------------------------
// ws layout: [bf16 codebooks 4MiB][cnorm f32 32KiB][idx i32 128KiB][hist i32 32KiB]
// ---------------------------------------------------------------------------
#define WS_CNORM_OFF  (4u*1024u*1024u)
#define WS_IDX_OFF    (WS_CNORM_OFF + N_CODES*4u)
#define WS_HIST_OFF   (WS_IDX_OFF + N_TOKENS*4u)

// ---------------------------------------------------------------------------
// K1: codebooks fp32 -> bf16, ||c||^2, zero histogram.
// ---------------------------------------------------------------------------
__global__ __launch_bounds__(256) void k_prep(const float* __restrict__ cbf,
                                              unsigned short* __restrict__ cbh,
                                              float* __restrict__ cnorm,
                                              int* __restrict__ hist) {
    const int tid = blockIdx.x * 256 + threadIdx.x;
    if (tid < N_CODES) hist[tid] = 0;

    const int w = threadIdx.x >> 6;
    const int lane = threadIdx.x & 63;
    const int row = blockIdx.x * 4 + w;

    const float4 v = ((const float4*)(cbf + (size_t)row * DIM))[lane];
    float sq = v.x * v.x + v.y * v.y + v.z * v.z + v.w * v.w;

    ushort4 u;
    u.x = __builtin_bit_cast(unsigned short, (__bf16)v.x);
    u.y = __builtin_bit_cast(unsigned short, (__bf16)v.y);
    u.z = __builtin_bit_cast(unsigned short, (__bf16)v.z);
    u.w = __builtin_bit_cast(unsigned short, (__bf16)v.w);
    ((ushort4*)(cbh + (size_t)row * DIM))[lane] = u;

    #pragma unroll
    for (int d = 1; d < 64; d <<= 1) sq += __shfl_xor(sq, d);
    if (lane == 0) cnorm[row] = sq;
}

// ---------------------------------------------------------------------------
// K2: fused distance-matmul + argmin, v2.
//  - A (64 tokens x 256 dims, bf16) in registers: 4 mf x 8 kc frags = 128 VGPR
//  - B staged via global_load_lds (16B), double-buffered 2x32KB, per-wave
//    private regions (wave w stages and reads codes [16w,16w+16) of a chunk)
//    -> NO __syncthreads in the main loop, only s_waitcnt vmcnt(0) per chunk.
//  - XOR-swizzle at 16B granularity: element (c, j) lives at slot
//    (c, (j+c)&31). Staging swizzles per-lane SOURCE addresses (LDS dest of
//    global_load_lds is fixed base+lane*16); reads apply the same swizzle.
//    -> 8 lanes per bank-quad, conflict-free, all accesses 16B aligned.
// ---------------------------------------------------------------------------
__global__ __launch_bounds__(256, 1) void k_argmin(const float* __restrict__ X,
                                                   const unsigned short* __restrict__ cbh,
                                                   const float* __restrict__ cnorm,
                                                   int* __restrict__ idxout) {
    __shared__ __attribute__((aligned(16))) char Bs[2][32768];
    __shared__ float redv[4][64];
    __shared__ int   redi[4][64];

    const int tid  = threadIdx.x;
    const int w    = tid >> 6;
    const int lane = tid & 63;
    const int lr   = lane & 15;
    const int lq   = lane >> 4;
    const int r0   = blockIdx.x * 64;
    const int mycol = w * 16 + lr;            // code row within chunk this lane consumes

    // ---- staging source offsets (bytes within a 32KB chunk), one per instr s ----
    const int half = lane >> 5, l5 = lane & 31;
    int srcoff[8];
    #pragma unroll
    for (int s = 0; s < 8; ++s) {
        const int c = w * 16 + 2 * s + half;  // code row this lane helps stage
        const int j = (l5 - c) & 31;          // global 16B-chunk that lands in slot l5
        srcoff[s] = c * 512 + j * 16;
    }
    const char* cbb = (const char*)cbh;

    // ---- issue chunk 0 staging ----
    #pragma unroll
    for (int s = 0; s < 8; ++s)
        __builtin_amdgcn_global_load_lds(
            (const __attribute__((address_space(1))) unsigned int*)(cbb + srcoff[s]),
            (__attribute__((address_space(3))) unsigned int*)(&Bs[0][w * 8192 + s * 1024]),
            16, 0, 0);

    // ---- A fragments: 64 rows x 256 dims bf16 in registers ----
    bf16x8 A[4][8];
    #pragma unroll
    for (int mf = 0; mf < 4; ++mf) {
        const float* xr = X + (size_t)(r0 + mf * 16 + lr) * DIM;
        #pragma unroll
        for (int kc = 0; kc < 8; ++kc) {
            const float4 a0 = *(const float4*)(xr + kc * 32 + lq * 8);
            const float4 a1 = *(const float4*)(xr + kc * 32 + lq * 8 + 4);
            bf16x8 f;
            f[0] = (__bf16)a0.x; f[1] = (__bf16)a0.y; f[2] = (__bf16)a0.z; f[3] = (__bf16)a0.w;
            f[4] = (__bf16)a1.x; f[5] = (__bf16)a1.y; f[6] = (__bf16)a1.z; f[7] = (__bf16)a1.w;
            A[mf][kc] = f;
        }
    }

    float minv[16];
    int   mini[16];
    #pragma unroll
    for (int i = 0; i < 16; ++i) { minv[i] = 3.4e38f; mini[i] = 0; }

    for (int cc = 0; cc < 128; ++cc) {
        // previous chunk's staging (issued one full compute-phase ago) must be
        // in LDS before we read it. Per-wave wait; no block barrier needed.
        asm volatile("s_waitcnt vmcnt(0)" ::: "memory");

        // issue next chunk's staging; flies during this chunk's MFMAs
        if (cc + 1 < 128) {
            const char* src = cbb + (size_t)(cc + 1) * 32768;
            char* dst = &Bs[(cc + 1) & 1][w * 8192];
            #pragma unroll
            for (int s = 0; s < 8; ++s)
                __builtin_amdgcn_global_load_lds(
                    (const __attribute__((address_space(1))) unsigned int*)(src + srcoff[s]),
                    (__attribute__((address_space(3))) unsigned int*)(dst + s * 1024),
                    16, 0, 0);
        }

        const float cn = cnorm[cc * 64 + mycol];
        const char* bp = Bs[cc & 1] + mycol * 512;

        f32x4 acc[4];
        #pragma unroll
        for (int mf = 0; mf < 4; ++mf) {
            acc[mf][0] = 0.f; acc[mf][1] = 0.f; acc[mf][2] = 0.f; acc[mf][3] = 0.f;
        }

        #pragma unroll
        for (int kc = 0; kc < 8; ++kc) {
            const bf16x8 b = *(const bf16x8*)(bp + (((kc * 4 + lq + mycol) & 31) << 4));
            #pragma unroll
            for (int mf = 0; mf < 4; ++mf)
                acc[mf] = __builtin_amdgcn_mfma_f32_16x16x32_bf16(A[mf][kc], b, acc[mf], 0, 0, 0);
        }

        const int col = cc * 64 + mycol;
        #pragma unroll
        for (int mf = 0; mf < 4; ++mf)
            #pragma unroll
            for (int r = 0; r < 4; ++r) {
                const float d2 = fmaf(-2.f, acc[mf][r], cn);
                if (d2 < minv[mf * 4 + r]) { minv[mf * 4 + r] = d2; mini[mf * 4 + r] = col; }
            }
    }

    // ---- reduce across the 16 lanes sharing each token row ----
    #pragma unroll
    for (int mf = 0; mf < 4; ++mf)
        #pragma unroll
        for (int r = 0; r < 4; ++r) {
            float v = minv[mf * 4 + r]; int ix = mini[mf * 4 + r];
            #pragma unroll
            for (int d = 1; d <= 8; d <<= 1) {
                const float ov = __shfl_xor(v, d);
                const int   oi = __shfl_xor(ix, d);
                if (ov < v || (ov == v && oi < ix)) { v = ov; ix = oi; }
            }
            if (lr == 0) {
                const int row = mf * 16 + lq * 4 + r;
                redv[w][row] = v; redi[w][row] = ix;
            }
        }
    __syncthreads();

    // ---- reduce across the 4 waves (different code windows, same tokens) ----
    if (tid < 64) {
        float v = redv[0][tid]; int ix = redi[0][tid];
        #pragma unroll
        for (int ww = 1; ww < 4; ++ww) {
            const float ov = redv[ww][tid]; const int oi = redi[ww][tid];
            if (ov < v || (ov == v && oi < ix)) { v = ov; ix = oi; }
        }
        idxout[r0 + tid] = ix;
    }
}

// ---------------------------------------------------------------------------
// K3: exact fp32 epilogue: r_norm, n_norm, output write, histogram.
// ---------------------------------------------------------------------------
__global__ __launch_bounds__(256) void k_quant(const float* __restrict__ X,
                                               const float* __restrict__ R,
                                               const float* __restrict__ C,
                                               const int* __restrict__ idx,
                                               float* __restrict__ out,
                                               int* __restrict__ hist) {
    const int w = threadIdx.x >> 6;
    const int lane = threadIdx.x & 63;
    const int tok = blockIdx.x * 4 + w;
    const int k = idx[tok];

    const float4 x = ((const float4*)(X + (size_t)tok * DIM))[lane];
    const float4 r = ((const float4*)(R + (size_t)tok * DIM))[lane];
    const float4 c = ((const float4*)(C + (size_t)k * DIM))[lane];

    const float d0 = x.x - c.x, d1 = x.y - c.y, d2 = x.z - c.z, d3 = x.w - c.w;
    float r2 = d0 * d0 + d1 * d1 + d2 * d2 + d3 * d3;
    float n2 = r.x * r.x + r.y * r.y + r.z * r.z + r.w * r.w;
    #pragma unroll
    for (int d = 1; d < 64; d <<= 1) {
        r2 += __shfl_xor(r2, d);
        n2 += __shfl_xor(n2, d);
    }
    const float s = sqrtf(r2) / (sqrtf(n2) + EPSF);

    float4 o;
    o.x = fmaf(s, r.x, x.x);
    o.y = fmaf(s, r.y, x.y);
    o.z = fmaf(s, r.z, x.z);
    o.w = fmaf(s, r.w, x.w);
    ((float4*)(out + (size_t)tok * DIM))[lane] = o;

    if (lane == 0) atomicAdd(&hist[k], 1);
}

// ---------------------------------------------------------------------------
// K4: perplexity + num_unique from histogram. single block.
// ---------------------------------------------------------------------------
__global__ __launch_bounds__(256) void k_stats(const int* __restrict__ hist,
                                               float* __restrict__ outs) {
    float s = 0.f; int u = 0;
    for (int b = threadIdx.x; b < N_CODES; b += 256) {
        const float c = (float)hist[b];
        if (c > 0.f) ++u;
        const float p = c * (1.f / (float)N_TOKENS);
        s += p * logf(p + EPSF);
    }
    #pragma unroll
    for (int d = 1; d < 64; d <<= 1) {
        s += __shfl_xor(s, d);
        u += __shfl_xor(u, d);
    }
    __shared__ float ss[4];
    __shared__ int   su[4];
    const int w = threadIdx.x >> 6, lane = threadIdx.x & 63;
    if (lane == 0) { ss[w] = s; su[w] = u; }
    __syncthreads();
    if (threadIdx.x == 0) {
        const float st = ss[0] + ss[1] + ss[2] + ss[3];
        const int ut = su[0] + su[1] + su[2] + su[3];
        outs[0] = expf(-st);       // perplexity
        outs[1] = (float)ut;       // num_unique_indices
    }
}

// ---------------------------------------------------------------------------
extern "C" void kernel_launch(void* const* d_in, const int* in_sizes, int n_in,
                              void* d_out, int out_size, void* d_ws, size_t ws_size,
                              hipStream_t stream) {
    const float* X = (const float*)d_in[0];  // input_data (32768,256)
    const float* R = (const float*)d_in[1];  // rand       (32768,256)
    const float* C = (const float*)d_in[2];  // codebooks  (8192,256)
    float* out = (float*)d_out;

    char* ws = (char*)d_ws;
    unsigned short* cbh = (unsigned short*)ws;             // bf16 codebooks
    float* cnorm = (float*)(ws + WS_CNORM_OFF);
    int*   idx   = (int*)(ws + WS_IDX_OFF);
    int*   hist  = (int*)(ws + WS_HIST_OFF);

    k_prep  <<<N_CODES / 4,  256, 0, stream>>>(C, cbh, cnorm, hist);
    k_argmin<<<N_TOKENS / 64, 256, 0, stream>>>(X, cbh, cnorm, idx);
    k_quant <<<N_TOKENS / 4, 256, 0, stream>>>(X, R, C, idx, out, hist);
    k_stats <<<1, 256, 0, stream>>>(hist, out + (size_t)N_TOKENS * DIM);
}